// Round 11
// baseline (564.978 us; speedup 1.0000x reference)
//
#include <hip/hip_runtime.h>

// ---------------------------------------------------------------------------
// SAGE 3-layer GNN, fp32 — CSC scatter-atomic aggregation.
//
// Evidence log (R0-R10): dst-major GATHER aggregation is stuck at ~100us/
// layer under every structure: serial, prefetch-1, 8-wide ILP, bf16 rows,
// LDS-DMA staging, nt/L1-bypass, single-coop-kernel. Effective rate is
// always ~1 coalesced 256B group per CU per ~375ns (= HBM/L2 miss latency,
// m126) -> dependent random READ round-trips are the invariant bottleneck.
// R11 inverts: edges grouped by SRC (CSC). One wave per src reads its P row
// ONCE (sequential, coalesced) and scatters it into Hneigh[dst] with
// NO-RETURN global atomics (fire-and-forget: no latency round-trip, pure
// throughput). combine pass: h = act(S + Hn/deg) (+readout in layer 3).
// ---------------------------------------------------------------------------

#define DH 64
#define NG 16

__global__ void deg_count_kernel(const int* __restrict__ src, const int* __restrict__ dst,
                                 int* __restrict__ deg_dst, int* __restrict__ deg_src, int E) {
    int i = blockIdx.x * blockDim.x + threadIdx.x;
    if (i < E) {
        atomicAdd(&deg_dst[dst[i]], 1);
        atomicAdd(&deg_src[src[i]], 1);
    }
}

// single-block exclusive prefix scan (passed since R0) over deg_src -> col_lo
__global__ void scan_kernel(const int* __restrict__ deg, int* __restrict__ col_lo,
                            int* __restrict__ cursor, int M) {
    __shared__ int sdata[1024];
    __shared__ int s_base;
    int tid = threadIdx.x;
    if (tid == 0) s_base = 0;
    __syncthreads();
    for (int base = 0; base < M; base += 1024) {
        int v = (base + tid < M) ? deg[base + tid] : 0;
        sdata[tid] = v;
        __syncthreads();
        for (int off = 1; off < 1024; off <<= 1) {
            int t = (tid >= off) ? sdata[tid - off] : 0;
            __syncthreads();
            sdata[tid] += t;
            __syncthreads();
        }
        int excl = sdata[tid] - v;
        if (base + tid < M) {
            int rs = s_base + excl;
            col_lo[base + tid] = rs;
            cursor[base + tid] = rs;
        }
        __syncthreads();
        if (tid == 1023) s_base += sdata[1023];
        __syncthreads();
    }
    if (tid == 0) col_lo[M] = s_base;
}

// group edges by src: edge_dst[pos] = dst
__global__ void scatter_kernel(const int* __restrict__ src, const int* __restrict__ dst,
                               int* __restrict__ cursor, int* __restrict__ edge_dst, int E) {
    int i = blockIdx.x * blockDim.x + threadIdx.x;
    if (i < E) {
        int s = src[i];
        int p = atomicAdd(&cursor[s], 1);
        edge_dst[p] = dst[i];
    }
}

// S = X@Wself + b ; P = X@Wneigh.  X: M x K row-major, W: K x 64 row-major.
// (R5-passed version, unchanged)
template <int K>
__global__ __launch_bounds__(256) void gemm_dual_kernel(
    const float* __restrict__ X, const float* __restrict__ Ws_g,
    const float* __restrict__ Wn_g, const float* __restrict__ bias,
    float* __restrict__ S, float* __restrict__ P, int M) {
    __shared__ float Xs[64][68];   // stride 68: 16B-aligned float4 rows
    __shared__ float Ws[64][68];
    __shared__ float Wn[64][68];
    int tid = threadIdx.x;
    int row0 = blockIdx.x * 64;
    int cx = tid & 15;    // col group: cols cx + 16*i
    int ry = tid >> 4;    // row group: rows 4*ry + j
    float acc_s[4][4] = {{0.f}};
    float acc_n[4][4] = {{0.f}};

    for (int kc = 0; kc < K; kc += 64) {
#pragma unroll
        for (int it = 0; it < 4; ++it) {
            int q = tid + 256 * it;       // 0..1023
            int row = q >> 4;             // 0..63
            int k4 = (q & 15) * 4;        // 0..60
            float4 xv;
            int gr = row0 + row;
            if (gr < M)
                xv = *reinterpret_cast<const float4*>(&X[(size_t)gr * K + kc + k4]);
            else
                xv = make_float4(0.f, 0.f, 0.f, 0.f);
            *reinterpret_cast<float4*>(&Xs[row][k4]) = xv;
            float4 wv = *reinterpret_cast<const float4*>(&Ws_g[(size_t)(kc + row) * 64 + k4]);
            *reinterpret_cast<float4*>(&Ws[row][k4]) = wv;
            float4 nv = *reinterpret_cast<const float4*>(&Wn_g[(size_t)(kc + row) * 64 + k4]);
            *reinterpret_cast<float4*>(&Wn[row][k4]) = nv;
        }
        __syncthreads();
#pragma unroll 4
        for (int kk = 0; kk < 64; ++kk) {
            float a[4], bs[4], bn[4];
#pragma unroll
            for (int j = 0; j < 4; ++j) a[j] = Xs[ry * 4 + j][kk];
#pragma unroll
            for (int i = 0; i < 4; ++i) {
                bs[i] = Ws[kk][cx + 16 * i];
                bn[i] = Wn[kk][cx + 16 * i];
            }
#pragma unroll
            for (int j = 0; j < 4; ++j)
#pragma unroll
                for (int i = 0; i < 4; ++i) {
                    acc_s[j][i] += a[j] * bs[i];
                    acc_n[j][i] += a[j] * bn[i];
                }
        }
        __syncthreads();
    }

#pragma unroll
    for (int j = 0; j < 4; ++j) {
        int r = row0 + ry * 4 + j;
        if (r < M) {
#pragma unroll
            for (int i = 0; i < 4; ++i) {
                int c = cx + 16 * i;
                S[(size_t)r * DH + c] = acc_s[j][i] + bias[c];
                P[(size_t)r * DH + c] = acc_n[j][i];
            }
        }
    }
}

// one wave per SRC node: read P row once (coalesced stream), scatter into
// Hn[dst] via no-return atomics (fire-and-forget). 2 edges/iter for ILP.
__global__ __launch_bounds__(256) void scatter_agg_kernel(
    const float* __restrict__ P, const int* __restrict__ col_lo,
    const int* __restrict__ edge_dst, float* __restrict__ Hn, int M) {
    int tid = threadIdx.x;
    int lane = tid & 63;
    int s = blockIdx.x * 4 + (tid >> 6);
    if (s >= M) return;
    float p = P[((size_t)s << 6) + lane];   // sequential: wave reads 256B
    int lo = col_lo[s], hi = col_lo[s + 1];
    int e = lo;
    for (; e + 2 <= hi; e += 2) {
        int d0 = edge_dst[e];
        int d1 = edge_dst[e + 1];
        atomicAdd(&Hn[((size_t)d0 << 6) + lane], p);   // no return -> no stall
        atomicAdd(&Hn[((size_t)d1 << 6) + lane], p);
    }
    if (e < hi) {
        int d0 = edge_dst[e];
        atomicAdd(&Hn[((size_t)d0 << 6) + lane], p);
    }
}

// h = act(S + Hn/deg); layer-3 variant accumulates graph readout.
template <bool RELU, bool READOUT>
__global__ __launch_bounds__(256) void combine_kernel(
    const float* __restrict__ S, const float* __restrict__ Hn,
    const int* __restrict__ deg_dst, float* __restrict__ H,
    const int* __restrict__ graph_id, float* __restrict__ gsum,
    float* __restrict__ gcnt, int M) {
    int i = blockIdx.x * blockDim.x + threadIdx.x;   // one float4 per thread
    if (i >= M * 16) return;
    int n = i >> 4, t = i & 15;
    float inv = 1.0f / fmaxf((float)deg_dst[n], 1.0f);
    const float4 s = *reinterpret_cast<const float4*>(&S[((size_t)n << 6) + t * 4]);
    const float4 hn = *reinterpret_cast<const float4*>(&Hn[((size_t)n << 6) + t * 4]);
    float4 val;
    val.x = s.x + hn.x * inv;
    val.y = s.y + hn.y * inv;
    val.z = s.z + hn.z * inv;
    val.w = s.w + hn.w * inv;
    if (RELU) {
        val.x = fmaxf(val.x, 0.f); val.y = fmaxf(val.y, 0.f);
        val.z = fmaxf(val.z, 0.f); val.w = fmaxf(val.w, 0.f);
    }
    *reinterpret_cast<float4*>(&H[((size_t)n << 6) + t * 4]) = val;
    if (READOUT) {
        int gid = graph_id[n];
        atomicAdd(&gsum[gid * DH + t * 4 + 0], val.x);
        atomicAdd(&gsum[gid * DH + t * 4 + 1], val.y);
        atomicAdd(&gsum[gid * DH + t * 4 + 2], val.z);
        atomicAdd(&gsum[gid * DH + t * 4 + 3], val.w);
        if (t == 0) atomicAdd(&gcnt[gid], 1.0f);
    }
}

// single block of 1024: out_feat = gsum/cnt ; out = out_feat @ W_cls + b_cls
__global__ __launch_bounds__(1024) void readout_kernel(
    const float* __restrict__ gsum, const float* __restrict__ gcnt,
    const float* __restrict__ Wc, const float* __restrict__ bc,
    float* __restrict__ out, float* __restrict__ out_feat) {
    __shared__ float ofs[NG][DH];
    int tid = threadIdx.x;
    int g = tid >> 6, d = tid & 63;
    float of = gsum[tid] / fmaxf(gcnt[g], 1.0f);
    out_feat[tid] = of;
    ofs[g][d] = of;
    __syncthreads();
    if (tid < NG * 2) {
        int gg = tid >> 1, cc = tid & 1;
        float acc = bc[cc];
#pragma unroll 8
        for (int dd = 0; dd < DH; ++dd) acc += ofs[gg][dd] * Wc[dd * 2 + cc];
        out[gg * 2 + cc] = acc;
    }
}

extern "C" void kernel_launch(void* const* d_in, const int* in_sizes, int n_in,
                              void* d_out, int out_size, void* d_ws, size_t ws_size,
                              hipStream_t stream) {
    const float* feat     = (const float*)d_in[0];
    const int*   src      = (const int*)d_in[1];
    const int*   dst      = (const int*)d_in[2];
    const int*   graph_id = (const int*)d_in[3];
    const float* Ws1 = (const float*)d_in[4];
    const float* Wn1 = (const float*)d_in[5];
    const float* b1  = (const float*)d_in[6];
    const float* Ws2 = (const float*)d_in[7];
    const float* Wn2 = (const float*)d_in[8];
    const float* b2  = (const float*)d_in[9];
    const float* Ws3 = (const float*)d_in[10];
    const float* Wn3 = (const float*)d_in[11];
    const float* b3  = (const float*)d_in[12];
    const float* Wc  = (const float*)d_in[13];
    const float* bc  = (const float*)d_in[14];

    const int M = in_sizes[3];   // 10000 nodes
    const int E = in_sizes[1];   // 320000 edges

    float* out      = (float*)d_out;             // 16 x 2
    float* out_feat = out + NG * 2;              // 16 x 64
    float* Hbuf     = out_feat + NG * DH;        // 10000 x 64 (final h)

    // workspace layout (256B-aligned carves)
    char* w = (char*)d_ws;
    size_t off = 0;
    auto carve = [&](size_t bytes) {
        size_t o = off;
        off = (off + bytes + 255) & ~(size_t)255;
        return o;
    };
    int*   deg_dst  = (int*)  (w + carve((size_t)M * 4));
    int*   deg_src  = (int*)  (w + carve((size_t)M * 4));
    float* gsum     = (float*)(w + carve((size_t)NG * DH * 4));
    float* gcnt     = (float*)(w + carve((size_t)NG * 4));
    float* Hn       = (float*)(w + carve((size_t)M * DH * 4));
    size_t zero_bytes = off;   // deg_dst + deg_src + gsum + gcnt + Hn
    size_t hn_bytes = (size_t)M * DH * 4;
    int*   col_lo   = (int*)  (w + carve((size_t)(M + 1) * 4));
    int*   cursor   = (int*)  (w + carve((size_t)M * 4));
    int*   edge_dst = (int*)  (w + carve((size_t)E * 4));
    float* Sbuf     = (float*)(w + carve((size_t)M * DH * 4));
    float* Pbuf     = (float*)(w + carve((size_t)M * DH * 4));
    (void)ws_size; (void)n_in; (void)out_size;

    (void)hipMemsetAsync(d_ws, 0, zero_bytes, stream);

    int eb = (E + 255) / 256;
    deg_count_kernel<<<eb, 256, 0, stream>>>(src, dst, deg_dst, deg_src, E);
    scan_kernel<<<1, 1024, 0, stream>>>(deg_src, col_lo, cursor, M);
    scatter_kernel<<<eb, 256, 0, stream>>>(src, dst, cursor, edge_dst, E);

    int gb = (M + 63) / 64;        // gemm blocks
    int ab = (M + 3) / 4;          // scatter_agg blocks (wave per src)
    int cb = (M * 16 + 255) / 256; // combine blocks

    // layer 1 (K=256), relu
    gemm_dual_kernel<256><<<gb, 256, 0, stream>>>(feat, Ws1, Wn1, b1, Sbuf, Pbuf, M);
    scatter_agg_kernel<<<ab, 256, 0, stream>>>(Pbuf, col_lo, edge_dst, Hn, M);
    combine_kernel<true, false><<<cb, 256, 0, stream>>>(Sbuf, Hn, deg_dst, Hbuf,
                                                        graph_id, gsum, gcnt, M);
    (void)hipMemsetAsync(Hn, 0, hn_bytes, stream);
    // layer 2 (K=64), relu
    gemm_dual_kernel<64><<<gb, 256, 0, stream>>>(Hbuf, Ws2, Wn2, b2, Sbuf, Pbuf, M);
    scatter_agg_kernel<<<ab, 256, 0, stream>>>(Pbuf, col_lo, edge_dst, Hn, M);
    combine_kernel<true, false><<<cb, 256, 0, stream>>>(Sbuf, Hn, deg_dst, Hbuf,
                                                        graph_id, gsum, gcnt, M);
    (void)hipMemsetAsync(Hn, 0, hn_bytes, stream);
    // layer 3 (K=64), no relu, readout accumulation fused into combine
    gemm_dual_kernel<64><<<gb, 256, 0, stream>>>(Hbuf, Ws3, Wn3, b3, Sbuf, Pbuf, M);
    scatter_agg_kernel<<<ab, 256, 0, stream>>>(Pbuf, col_lo, edge_dst, Hn, M);
    combine_kernel<false, true><<<cb, 256, 0, stream>>>(Sbuf, Hn, deg_dst, Hbuf,
                                                        graph_id, gsum, gcnt, M);

    readout_kernel<<<1, 1024, 0, stream>>>(gsum, gcnt, Wc, bc, out, out_feat);
}

// Round 12
// 370.652 us; speedup vs baseline: 1.5243x; 1.5243x over previous
//
#include <hip/hip_runtime.h>

// ---------------------------------------------------------------------------
// SAGE 3-layer GNN, fp32 — multi-kernel (R5-passed structure).
//
// Evidence log:
//   R0-R10: gather agg ~140us invariant under 7 structural variants.
//   R11: combine_kernel (PURE coalesced streaming, VALUBusy 0.1%) ALSO takes
//     137us -> the gather was never the bottleneck. Common factor of every
//     slow kernel: it WRITES H into d_out (2.56MB / 137us = 19 GB/s, the
//     signature of an uncached/fine-grained output buffer). GEMMs (d_ws-only
//     writers) are always fast.
// R12: keep inter-layer H in d_ws; only layer-3 agg writes h to d_out (the
//   one mandatory slow write). Otherwise byte-identical to R5-passed kernel.
// ---------------------------------------------------------------------------

#define DH 64
#define NG 16

__global__ void deg_count_kernel(const int* __restrict__ dst, int* __restrict__ deg, int E) {
    int i = blockIdx.x * blockDim.x + threadIdx.x;
    if (i < E) atomicAdd(&deg[dst[i]], 1);
}

// single-block exclusive prefix scan over deg -> row_start (and cursor copy)
__global__ void scan_kernel(const int* __restrict__ deg, int* __restrict__ row_start,
                            int* __restrict__ cursor, int M) {
    __shared__ int sdata[1024];
    __shared__ int s_base;
    int tid = threadIdx.x;
    if (tid == 0) s_base = 0;
    __syncthreads();
    for (int base = 0; base < M; base += 1024) {
        int v = (base + tid < M) ? deg[base + tid] : 0;
        sdata[tid] = v;
        __syncthreads();
        for (int off = 1; off < 1024; off <<= 1) {
            int t = (tid >= off) ? sdata[tid - off] : 0;
            __syncthreads();
            sdata[tid] += t;
            __syncthreads();
        }
        int excl = sdata[tid] - v;
        if (base + tid < M) {
            int rs = s_base + excl;
            row_start[base + tid] = rs;
            cursor[base + tid] = rs;
        }
        __syncthreads();
        if (tid == 1023) s_base += sdata[1023];
        __syncthreads();
    }
    if (tid == 0) row_start[M] = s_base;
}

__global__ void scatter_kernel(const int* __restrict__ src, const int* __restrict__ dst,
                               int* __restrict__ cursor, int* __restrict__ edge_src, int E) {
    int i = blockIdx.x * blockDim.x + threadIdx.x;
    if (i < E) {
        int d = dst[i];
        int p = atomicAdd(&cursor[d], 1);
        edge_src[p] = src[i];
    }
}

// S = X@Wself + b ; P = X@Wneigh.  X: M x K row-major, W: K x 64 row-major.
// (R5-passed version, unchanged)
template <int K>
__global__ __launch_bounds__(256) void gemm_dual_kernel(
    const float* __restrict__ X, const float* __restrict__ Ws_g,
    const float* __restrict__ Wn_g, const float* __restrict__ bias,
    float* __restrict__ S, float* __restrict__ P, int M) {
    __shared__ float Xs[64][68];   // stride 68: 16B-aligned float4 rows
    __shared__ float Ws[64][68];
    __shared__ float Wn[64][68];
    int tid = threadIdx.x;
    int row0 = blockIdx.x * 64;
    int cx = tid & 15;    // col group: cols cx + 16*i
    int ry = tid >> 4;    // row group: rows 4*ry + j
    float acc_s[4][4] = {{0.f}};
    float acc_n[4][4] = {{0.f}};

    for (int kc = 0; kc < K; kc += 64) {
#pragma unroll
        for (int it = 0; it < 4; ++it) {
            int q = tid + 256 * it;       // 0..1023
            int row = q >> 4;             // 0..63
            int k4 = (q & 15) * 4;        // 0..60
            float4 xv;
            int gr = row0 + row;
            if (gr < M)
                xv = *reinterpret_cast<const float4*>(&X[(size_t)gr * K + kc + k4]);
            else
                xv = make_float4(0.f, 0.f, 0.f, 0.f);
            *reinterpret_cast<float4*>(&Xs[row][k4]) = xv;
            float4 wv = *reinterpret_cast<const float4*>(&Ws_g[(size_t)(kc + row) * 64 + k4]);
            *reinterpret_cast<float4*>(&Ws[row][k4]) = wv;
            float4 nv = *reinterpret_cast<const float4*>(&Wn_g[(size_t)(kc + row) * 64 + k4]);
            *reinterpret_cast<float4*>(&Wn[row][k4]) = nv;
        }
        __syncthreads();
#pragma unroll 4
        for (int kk = 0; kk < 64; ++kk) {
            float a[4], bs[4], bn[4];
#pragma unroll
            for (int j = 0; j < 4; ++j) a[j] = Xs[ry * 4 + j][kk];
#pragma unroll
            for (int i = 0; i < 4; ++i) {
                bs[i] = Ws[kk][cx + 16 * i];
                bn[i] = Wn[kk][cx + 16 * i];
            }
#pragma unroll
            for (int j = 0; j < 4; ++j)
#pragma unroll
                for (int i = 0; i < 4; ++i) {
                    acc_s[j][i] += a[j] * bs[i];
                    acc_n[j][i] += a[j] * bn[i];
                }
        }
        __syncthreads();
    }

#pragma unroll
    for (int j = 0; j < 4; ++j) {
        int r = row0 + ry * 4 + j;
        if (r < M) {
#pragma unroll
            for (int i = 0; i < 4; ++i) {
                int c = cx + 16 * i;
                S[(size_t)r * DH + c] = acc_s[j][i] + bias[c];
                P[(size_t)r * DH + c] = acc_n[j][i];
            }
        }
    }
}

// one wave per node; wave = 4 edge-groups (g) x 16 lanes (t), float4 per lane.
// R5-passed inner loop (clamp + fmaf mask, 8 idx + 8 row loads).
template <bool RELU, bool READOUT>
__global__ __launch_bounds__(256) void agg_kernel(
    const float* __restrict__ S, const float* __restrict__ P,
    const int* __restrict__ row_start, const int* __restrict__ edge_src,
    float* __restrict__ H, const int* __restrict__ graph_id,
    float* __restrict__ gsum, float* __restrict__ gcnt, int M) {
    int tid = threadIdx.x;
    int lane = tid & 63;
    int n = blockIdx.x * 4 + (tid >> 6);
    if (n >= M) return;
    int g = lane >> 4;    // edge group: slot covers edges e+4k+g
    int t = lane & 15;    // float4 chunk of row

    int e0 = row_start[n], e1 = row_start[n + 1];
    int deg = e1 - e0;

    float ax = 0.f, ay = 0.f, az = 0.f, aw = 0.f;
    for (int e = e0; e < e1; e += 32) {
        int c = e1 - 1;   // valid clamp target (loop body implies e1 >= 1)
        int q0 = e + g,      q1 = e + 4 + g,  q2 = e + 8 + g,  q3 = e + 12 + g;
        int q4 = e + 16 + g, q5 = e + 20 + g, q6 = e + 24 + g, q7 = e + 28 + g;
        int i0 = edge_src[min(q0, c)];
        int i1 = edge_src[min(q1, c)];
        int i2 = edge_src[min(q2, c)];
        int i3 = edge_src[min(q3, c)];
        int i4 = edge_src[min(q4, c)];
        int i5 = edge_src[min(q5, c)];
        int i6 = edge_src[min(q6, c)];
        int i7 = edge_src[min(q7, c)];
        float m0 = (q0 < e1) ? 1.f : 0.f;
        float m1 = (q1 < e1) ? 1.f : 0.f;
        float m2 = (q2 < e1) ? 1.f : 0.f;
        float m3 = (q3 < e1) ? 1.f : 0.f;
        float m4 = (q4 < e1) ? 1.f : 0.f;
        float m5 = (q5 < e1) ? 1.f : 0.f;
        float m6 = (q6 < e1) ? 1.f : 0.f;
        float m7 = (q7 < e1) ? 1.f : 0.f;
        float4 a0 = *reinterpret_cast<const float4*>(&P[((size_t)i0 << 6) + t * 4]);
        float4 a1 = *reinterpret_cast<const float4*>(&P[((size_t)i1 << 6) + t * 4]);
        float4 a2 = *reinterpret_cast<const float4*>(&P[((size_t)i2 << 6) + t * 4]);
        float4 a3 = *reinterpret_cast<const float4*>(&P[((size_t)i3 << 6) + t * 4]);
        float4 a4 = *reinterpret_cast<const float4*>(&P[((size_t)i4 << 6) + t * 4]);
        float4 a5 = *reinterpret_cast<const float4*>(&P[((size_t)i5 << 6) + t * 4]);
        float4 a6 = *reinterpret_cast<const float4*>(&P[((size_t)i6 << 6) + t * 4]);
        float4 a7 = *reinterpret_cast<const float4*>(&P[((size_t)i7 << 6) + t * 4]);
        ax = fmaf(m0, a0.x, ax); ay = fmaf(m0, a0.y, ay); az = fmaf(m0, a0.z, az); aw = fmaf(m0, a0.w, aw);
        ax = fmaf(m1, a1.x, ax); ay = fmaf(m1, a1.y, ay); az = fmaf(m1, a1.z, az); aw = fmaf(m1, a1.w, aw);
        ax = fmaf(m2, a2.x, ax); ay = fmaf(m2, a2.y, ay); az = fmaf(m2, a2.z, az); aw = fmaf(m2, a2.w, aw);
        ax = fmaf(m3, a3.x, ax); ay = fmaf(m3, a3.y, ay); az = fmaf(m3, a3.z, az); aw = fmaf(m3, a3.w, aw);
        ax = fmaf(m4, a4.x, ax); ay = fmaf(m4, a4.y, ay); az = fmaf(m4, a4.z, az); aw = fmaf(m4, a4.w, aw);
        ax = fmaf(m5, a5.x, ax); ay = fmaf(m5, a5.y, ay); az = fmaf(m5, a5.z, az); aw = fmaf(m5, a5.w, aw);
        ax = fmaf(m6, a6.x, ax); ay = fmaf(m6, a6.y, ay); az = fmaf(m6, a6.z, az); aw = fmaf(m6, a6.w, aw);
        ax = fmaf(m7, a7.x, ax); ay = fmaf(m7, a7.y, ay); az = fmaf(m7, a7.z, az); aw = fmaf(m7, a7.w, aw);
    }

    // reduce across the 4 edge-groups (lanes t, t+16, t+32, t+48)
#pragma unroll
    for (int m = 16; m <= 32; m <<= 1) {
        ax += __shfl_xor(ax, m, 64);
        ay += __shfl_xor(ay, m, 64);
        az += __shfl_xor(az, m, 64);
        aw += __shfl_xor(aw, m, 64);
    }

    if (g == 0) {
        float inv = 1.0f / fmaxf((float)deg, 1.0f);
        const float4 s = *reinterpret_cast<const float4*>(&S[(size_t)n * DH + t * 4]);
        float4 val;
        val.x = s.x + ax * inv;
        val.y = s.y + ay * inv;
        val.z = s.z + az * inv;
        val.w = s.w + aw * inv;
        if (RELU) {
            val.x = fmaxf(val.x, 0.f); val.y = fmaxf(val.y, 0.f);
            val.z = fmaxf(val.z, 0.f); val.w = fmaxf(val.w, 0.f);
        }
        *reinterpret_cast<float4*>(&H[(size_t)n * DH + t * 4]) = val;
        if (READOUT) {
            int gid = graph_id[n];
            atomicAdd(&gsum[gid * DH + t * 4 + 0], val.x);
            atomicAdd(&gsum[gid * DH + t * 4 + 1], val.y);
            atomicAdd(&gsum[gid * DH + t * 4 + 2], val.z);
            atomicAdd(&gsum[gid * DH + t * 4 + 3], val.w);
            if (t == 0) atomicAdd(&gcnt[gid], 1.0f);
        }
    }
}

// single block of 1024: out_feat = gsum/cnt ; out = out_feat @ W_cls + b_cls
__global__ __launch_bounds__(1024) void readout_kernel(
    const float* __restrict__ gsum, const float* __restrict__ gcnt,
    const float* __restrict__ Wc, const float* __restrict__ bc,
    float* __restrict__ out, float* __restrict__ out_feat) {
    __shared__ float ofs[NG][DH];
    int tid = threadIdx.x;
    int g = tid >> 6, d = tid & 63;
    float of = gsum[tid] / fmaxf(gcnt[g], 1.0f);
    out_feat[tid] = of;
    ofs[g][d] = of;
    __syncthreads();
    if (tid < NG * 2) {
        int gg = tid >> 1, cc = tid & 1;
        float acc = bc[cc];
#pragma unroll 8
        for (int dd = 0; dd < DH; ++dd) acc += ofs[gg][dd] * Wc[dd * 2 + cc];
        out[gg * 2 + cc] = acc;
    }
}

extern "C" void kernel_launch(void* const* d_in, const int* in_sizes, int n_in,
                              void* d_out, int out_size, void* d_ws, size_t ws_size,
                              hipStream_t stream) {
    const float* feat     = (const float*)d_in[0];
    const int*   src      = (const int*)d_in[1];
    const int*   dst      = (const int*)d_in[2];
    const int*   graph_id = (const int*)d_in[3];
    const float* Ws1 = (const float*)d_in[4];
    const float* Wn1 = (const float*)d_in[5];
    const float* b1  = (const float*)d_in[6];
    const float* Ws2 = (const float*)d_in[7];
    const float* Wn2 = (const float*)d_in[8];
    const float* b2  = (const float*)d_in[9];
    const float* Ws3 = (const float*)d_in[10];
    const float* Wn3 = (const float*)d_in[11];
    const float* b3  = (const float*)d_in[12];
    const float* Wc  = (const float*)d_in[13];
    const float* bc  = (const float*)d_in[14];

    const int M = in_sizes[3];   // 10000 nodes
    const int E = in_sizes[1];   // 320000 edges

    float* out      = (float*)d_out;             // 16 x 2
    float* out_feat = out + NG * 2;              // 16 x 64
    float* h_out    = out_feat + NG * DH;        // 10000 x 64 (final h, d_out)

    // workspace layout (256B-aligned carves)
    char* w = (char*)d_ws;
    size_t off = 0;
    auto carve = [&](size_t bytes) {
        size_t o = off;
        off = (off + bytes + 255) & ~(size_t)255;
        return o;
    };
    int*   deg      = (int*)  (w + carve((size_t)M * 4));
    float* gsum     = (float*)(w + carve((size_t)NG * DH * 4));
    float* gcnt     = (float*)(w + carve((size_t)NG * 4));
    size_t zero_bytes = off;                       // deg + gsum + gcnt
    int*   row_start = (int*)  (w + carve((size_t)(M + 1) * 4));
    int*   cursor    = (int*)  (w + carve((size_t)M * 4));
    int*   edge_src  = (int*)  (w + carve((size_t)E * 4));
    float* Sbuf      = (float*)(w + carve((size_t)M * DH * 4));
    float* Pbuf      = (float*)(w + carve((size_t)M * DH * 4));
    float* Hws       = (float*)(w + carve((size_t)M * DH * 4));   // inter-layer H (d_ws!)
    (void)ws_size; (void)n_in; (void)out_size;

    (void)hipMemsetAsync(d_ws, 0, zero_bytes, stream);

    int eb = (E + 255) / 256;
    deg_count_kernel<<<eb, 256, 0, stream>>>(dst, deg, E);
    scan_kernel<<<1, 1024, 0, stream>>>(deg, row_start, cursor, M);
    scatter_kernel<<<eb, 256, 0, stream>>>(src, dst, cursor, edge_src, E);

    int gb = (M + 63) / 64;   // gemm blocks
    int ab = (M + 3) / 4;     // agg blocks

    // layer 1 (K=256), relu — H stays in d_ws
    gemm_dual_kernel<256><<<gb, 256, 0, stream>>>(feat, Ws1, Wn1, b1, Sbuf, Pbuf, M);
    agg_kernel<true, false><<<ab, 256, 0, stream>>>(Sbuf, Pbuf, row_start, edge_src,
                                                    Hws, graph_id, gsum, gcnt, M);
    // layer 2 (K=64), relu — H stays in d_ws
    gemm_dual_kernel<64><<<gb, 256, 0, stream>>>(Hws, Ws2, Wn2, b2, Sbuf, Pbuf, M);
    agg_kernel<true, false><<<ab, 256, 0, stream>>>(Sbuf, Pbuf, row_start, edge_src,
                                                    Hws, graph_id, gsum, gcnt, M);
    // layer 3 (K=64), no relu, fused readout — h written ONCE to d_out
    gemm_dual_kernel<64><<<gb, 256, 0, stream>>>(Hws, Ws3, Wn3, b3, Sbuf, Pbuf, M);
    agg_kernel<false, true><<<ab, 256, 0, stream>>>(Sbuf, Pbuf, row_start, edge_src,
                                                    h_out, graph_id, gsum, gcnt, M);

    readout_kernel<<<1, 1024, 0, stream>>>(gsum, gcnt, Wc, bc, out, out_feat);
}